// Round 5
// baseline (198.016 us; speedup 1.0000x reference)
//
#include <hip/hip_runtime.h>

// ForwardKinematics, fp32: rotations (B,24,4) wxyz + positions (B,24,3)
// -> global joint positions (B,24,3). Fixed SMPL tree.
//
// Round 5: round-4 design with the nontemporal-store type fixed (native
// clang vector instead of HIP_vector_type float4).
//   - 2 threads per sample (kinematic subtree split): doubles wave count;
//     round 3 was latency-bound at the 25% occupancy ceiling.
//   - group 0: joints 0..11 (ancestor-closed), writes floats [0,36) of sample
//   - group 1: joints 12..23, re-derives spine {0,3,6,9}, writes [36,72)
//   - nontemporal stores on output to kill write-allocate over-fetch.

typedef float f32x4 __attribute__((ext_vector_type(4)));

struct M { float r0,r1,r2,r3,r4,r5,r6,r7,r8,tx,ty,tz; };

__device__ __forceinline__ M loc(f32x4 q, float px, float py, float pz) {
    float inv = rsqrtf(q.x*q.x + q.y*q.y + q.z*q.z + q.w*q.w);
    float qw = q.x*inv, qx = q.y*inv, qy = q.z*inv, qz = q.w*inv;
    float x2 = qx+qx, y2 = qy+qy, z2 = qz+qz;
    float xx = qx*x2, yy = qy*y2, zz = qz*z2;
    float xy = qx*y2, yz = qy*z2, xz = qx*z2;
    float wx = qw*x2, wy = qw*y2, wz = qw*z2;
    M m;
    m.r0 = 1.f-(yy+zz); m.r1 = xy-wz;       m.r2 = xz+wy;
    m.r3 = xy+wz;       m.r4 = 1.f-(xx+zz); m.r5 = yz-wx;
    m.r6 = xz-wy;       m.r7 = yz+wx;       m.r8 = 1.f-(xx+yy);
    m.tx = px; m.ty = py; m.tz = pz;
    return m;
}

__device__ __forceinline__ M mul(const M& a, const M& b) {
    M c;
    c.r0 = a.r0*b.r0 + a.r1*b.r3 + a.r2*b.r6;
    c.r1 = a.r0*b.r1 + a.r1*b.r4 + a.r2*b.r7;
    c.r2 = a.r0*b.r2 + a.r1*b.r5 + a.r2*b.r8;
    c.r3 = a.r3*b.r0 + a.r4*b.r3 + a.r5*b.r6;
    c.r4 = a.r3*b.r1 + a.r4*b.r4 + a.r5*b.r7;
    c.r5 = a.r3*b.r2 + a.r4*b.r5 + a.r5*b.r8;
    c.r6 = a.r6*b.r0 + a.r7*b.r3 + a.r8*b.r6;
    c.r7 = a.r6*b.r1 + a.r7*b.r4 + a.r8*b.r7;
    c.r8 = a.r6*b.r2 + a.r7*b.r5 + a.r8*b.r8;
    c.tx = a.r0*b.tx + a.r1*b.ty + a.r2*b.tz + a.tx;
    c.ty = a.r3*b.tx + a.r4*b.ty + a.r5*b.tz + a.ty;
    c.tz = a.r6*b.tx + a.r7*b.ty + a.r8*b.tz + a.tz;
    return c;
}

__global__ __launch_bounds__(256) void fk_kernel(
    const f32x4* __restrict__ rot4,   // B*24 vec4 (quat wxyz per joint)
    const float* __restrict__ pos,    // B*72 floats
    f32x4* __restrict__ out4,         // B*18 vec4
    int B)
{
    const int t = blockIdx.x * blockDim.x + threadIdx.x;
    const int b = t >> 1;
    if (b >= B) return;
    const int g = t & 1;

    const f32x4* rq = rot4 + (size_t)b * 24;
    const float* pp = pos  + (size_t)b * 72;
    f32x4*       op = out4 + (size_t)b * 18;

    float o[36];   // this half-sample's 36 output floats (static idx -> VGPRs)

    if (g == 0) {
        // ---- joints 0..11 (parents all within 0..9) ----
        constexpr int PAR[12] = {-1, 0, 0, 0, 1, 2, 3, 4, 5, 6, 7, 8};
        M G[12];
        G[0] = loc(rq[0], pp[0], pp[1], pp[2]);
#pragma unroll
        for (int j = 1; j < 12; ++j)
            G[j] = mul(G[PAR[j]], loc(rq[j], pp[3*j], pp[3*j+1], pp[3*j+2]));
#pragma unroll
        for (int j = 0; j < 12; ++j) {
            o[3*j+0] = G[j].tx; o[3*j+1] = G[j].ty; o[3*j+2] = G[j].tz;
        }
#pragma unroll
        for (int i = 0; i < 9; ++i) {
            f32x4 v = {o[4*i], o[4*i+1], o[4*i+2], o[4*i+3]};
            __builtin_nontemporal_store(v, op + i);
        }
    } else {
        // ---- joints 12..23; re-derive spine chain {0,3,6,9} ----
        // local index k -> joint JL[k]; parent (local index) P[k]
        constexpr int JL[16] = {0,3,6,9, 12,13,14,15,16,17,18,19,20,21,22,23};
        constexpr int P [16] = {-1,0,1,2, 3,3,3,4,5,6,8,9,10,11,12,13};
        M G[16];
#pragma unroll
        for (int k = 0; k < 16; ++k) {
            const int j = JL[k];
            M l = loc(rq[j], pp[3*j], pp[3*j+1], pp[3*j+2]);
            G[k] = (k == 0) ? l : mul(G[P[k]], l);
        }
#pragma unroll
        for (int k = 4; k < 16; ++k) {
            const int j = JL[k] - 12;      // 0..11 within this half
            o[3*j+0] = G[k].tx; o[3*j+1] = G[k].ty; o[3*j+2] = G[k].tz;
        }
#pragma unroll
        for (int i = 0; i < 9; ++i) {
            f32x4 v = {o[4*i], o[4*i+1], o[4*i+2], o[4*i+3]};
            __builtin_nontemporal_store(v, op + 9 + i);
        }
    }
}

extern "C" void kernel_launch(void* const* d_in, const int* in_sizes, int n_in,
                              void* d_out, int out_size, void* d_ws, size_t ws_size,
                              hipStream_t stream) {
    const int B = out_size / 72;           // (B,24,3)
    const void* rot = nullptr;
    const void* pos = nullptr;
    for (int i = 0; i < n_in; ++i) {       // resolve by size, not order
        if      (in_sizes[i] == B * 96) rot = d_in[i];
        else if (in_sizes[i] == B * 72) pos = d_in[i];
    }
    if (!rot) rot = d_in[2];
    if (!pos) pos = d_in[1];

    const int threads = 2 * B;             // 2 threads per sample
    const int block = 256;
    const int grid = (threads + block - 1) / block;
    fk_kernel<<<grid, block, 0, stream>>>(
        (const f32x4*)rot, (const float*)pos, (f32x4*)d_out, B);
}

// Round 6
// 139.874 us; speedup vs baseline: 1.4157x; 1.4157x over previous
//
#include <hip/hip_runtime.h>

// ForwardKinematics, fp32: rotations (B,24,4) wxyz + positions (B,24,3)
// -> global joint positions (B,24,3). Fixed SMPL tree.
//
// Round 6:
//  - 2 threads/sample, WAVE-uniform split (wave w -> g=w&1): no divergence.
//      g=0: joints 0..11 (ancestor-closed)
//      g=1: joints 12..23 (re-derives spine 0,3,6,9; redundant VALU is cheap)
//  - Output staged in LDS (pitch 77 dwords/sample, odd -> conflict-free),
//    then block-coalesced DENSE stores (full-line coverage -> no RFO, no
//    partial-line write amplification; rounds 3/5 lost 2-3.2x here).
//  - Cached (non-nt) stores.

typedef float f32x4 __attribute__((ext_vector_type(4)));

struct M { float r0,r1,r2,r3,r4,r5,r6,r7,r8,tx,ty,tz; };

__device__ __forceinline__ M loc(f32x4 q, float px, float py, float pz) {
    float inv = rsqrtf(q.x*q.x + q.y*q.y + q.z*q.z + q.w*q.w);
    float qw = q.x*inv, qx = q.y*inv, qy = q.z*inv, qz = q.w*inv;
    float x2 = qx+qx, y2 = qy+qy, z2 = qz+qz;
    float xx = qx*x2, yy = qy*y2, zz = qz*z2;
    float xy = qx*y2, yz = qy*z2, xz = qx*z2;
    float wx = qw*x2, wy = qw*y2, wz = qw*z2;
    M m;
    m.r0 = 1.f-(yy+zz); m.r1 = xy-wz;       m.r2 = xz+wy;
    m.r3 = xy+wz;       m.r4 = 1.f-(xx+zz); m.r5 = yz-wx;
    m.r6 = xz-wy;       m.r7 = yz+wx;       m.r8 = 1.f-(xx+yy);
    m.tx = px; m.ty = py; m.tz = pz;
    return m;
}

__device__ __forceinline__ M mul(const M& a, const M& b) {
    M c;
    c.r0 = a.r0*b.r0 + a.r1*b.r3 + a.r2*b.r6;
    c.r1 = a.r0*b.r1 + a.r1*b.r4 + a.r2*b.r7;
    c.r2 = a.r0*b.r2 + a.r1*b.r5 + a.r2*b.r8;
    c.r3 = a.r3*b.r0 + a.r4*b.r3 + a.r5*b.r6;
    c.r4 = a.r3*b.r1 + a.r4*b.r4 + a.r5*b.r7;
    c.r5 = a.r3*b.r2 + a.r4*b.r5 + a.r5*b.r8;
    c.r6 = a.r6*b.r0 + a.r7*b.r3 + a.r8*b.r6;
    c.r7 = a.r6*b.r1 + a.r7*b.r4 + a.r8*b.r7;
    c.r8 = a.r6*b.r2 + a.r7*b.r5 + a.r8*b.r8;
    c.tx = a.r0*b.tx + a.r1*b.ty + a.r2*b.tz + a.tx;
    c.ty = a.r3*b.tx + a.r4*b.ty + a.r5*b.tz + a.ty;
    c.tz = a.r6*b.tx + a.r7*b.ty + a.r8*b.tz + a.tz;
    return c;
}

#define SPB  128   // samples per block (256 threads, 2 threads/sample)
#define PADW 77    // LDS pitch in dwords per sample (72 data + 5 pad, odd)

__global__ __launch_bounds__(256) void fk_kernel(
    const f32x4* __restrict__ rot4,   // B*24 vec4 (quat wxyz per joint)
    const float* __restrict__ pos,    // B*72 floats
    float*       __restrict__ out,    // B*72 floats
    int B)
{
    __shared__ float lds[SPB * PADW];   // 39424 B -> 4 blocks/CU

    const int t  = threadIdx.x;
    const int w  = t >> 6, l = t & 63;
    const int g  = w & 1;                       // wave-uniform subtree id
    const int sl = ((w >> 1) << 6) + l;         // local sample 0..127
    const int b  = blockIdx.x * SPB + sl;

    if (b < B) {
        const f32x4* rq = rot4 + (size_t)b * 24;
        const float* pp = pos  + (size_t)b * 72;
        float o[36];

        if (g == 0) {
            // ---- joints 0..11 ----
            float tl[36];
            const f32x4* pc = (const f32x4*)pp;          // floats [0,36)
#pragma unroll
            for (int i = 0; i < 9; ++i) {
                f32x4 v = pc[i];
                tl[4*i+0]=v.x; tl[4*i+1]=v.y; tl[4*i+2]=v.z; tl[4*i+3]=v.w;
            }
            constexpr int PAR[12] = {-1, 0, 0, 0, 1, 2, 3, 4, 5, 6, 7, 8};
            M G[12];
            G[0] = loc(rq[0], tl[0], tl[1], tl[2]);
#pragma unroll
            for (int j = 1; j < 12; ++j)
                G[j] = mul(G[PAR[j]], loc(rq[j], tl[3*j], tl[3*j+1], tl[3*j+2]));
#pragma unroll
            for (int j = 0; j < 12; ++j) {
                o[3*j+0] = G[j].tx; o[3*j+1] = G[j].ty; o[3*j+2] = G[j].tz;
            }
        } else {
            // ---- joints 12..23 (re-derive spine 0->3->6->9) ----
            float tc[36];                                 // floats [36,72)
            const f32x4* pc = (const f32x4*)(pp + 36);
#pragma unroll
            for (int i = 0; i < 9; ++i) {
                f32x4 v = pc[i];
                tc[4*i+0]=v.x; tc[4*i+1]=v.y; tc[4*i+2]=v.z; tc[4*i+3]=v.w;
            }
            M G[16];
            G[0] = loc(rq[0], pp[0],  pp[1],  pp[2]);
            G[1] = mul(G[0], loc(rq[3], pp[9],  pp[10], pp[11]));
            G[2] = mul(G[1], loc(rq[6], pp[18], pp[19], pp[20]));
            G[3] = mul(G[2], loc(rq[9], pp[27], pp[28], pp[29]));
            // joints 12+j, parents as local indices into G[]
            constexpr int P[12] = {3,3,3, 4,5,6, 8,9,10, 11,12,13};
#pragma unroll
            for (int j = 0; j < 12; ++j)
                G[4+j] = mul(G[P[j]], loc(rq[12+j], tc[3*j], tc[3*j+1], tc[3*j+2]));
#pragma unroll
            for (int j = 0; j < 12; ++j) {
                o[3*j+0] = G[4+j].tx; o[3*j+1] = G[4+j].ty; o[3*j+2] = G[4+j].tz;
            }
        }

        // stage to LDS: dword index 77*sl + 36*g + e  (77l mod 32 hits all
        // banks -> 2-way aliasing only = free)
        float* ld = lds + sl * PADW + g * 36;
#pragma unroll
        for (int e = 0; e < 36; ++e) ld[e] = o[e];
    }

    __syncthreads();

    // Coalesced unload: this block owns floats [blockIdx*9216, +9216).
    // Instruction n: lane t stores float F = n*256+t -> dense 1-KB/wave,
    // full-line coverage (no RFO, no partial-line writes).
    const size_t base = (size_t)blockIdx.x * (SPB * 72);
    const size_t lim  = (size_t)B * 72;
#pragma unroll
    for (int n = 0; n < 36; ++n) {
        const int F = n * 256 + t;          // 0..9215
        const int s = F / 72;               // magic-mul, compile-time const 72
        const int r = F - s * 72;
        const size_t gi = base + F;
        if (gi < lim) out[gi] = lds[s * PADW + r];
    }
}

extern "C" void kernel_launch(void* const* d_in, const int* in_sizes, int n_in,
                              void* d_out, int out_size, void* d_ws, size_t ws_size,
                              hipStream_t stream) {
    const int B = out_size / 72;           // (B,24,3)
    const void* rot = nullptr;
    const void* pos = nullptr;
    for (int i = 0; i < n_in; ++i) {       // resolve by size, not order
        if      (in_sizes[i] == B * 96) rot = d_in[i];
        else if (in_sizes[i] == B * 72) pos = d_in[i];
    }
    if (!rot) rot = d_in[2];
    if (!pos) pos = d_in[1];

    const int grid = (B + SPB - 1) / SPB;  // 1024 blocks @ B=131072
    fk_kernel<<<grid, 256, 0, stream>>>(
        (const f32x4*)rot, (const float*)pos, (float*)d_out, B);
}